// Round 1
// baseline (238.623 us; speedup 1.0000x reference)
//
#include <hip/hip_runtime.h>

#define NN 50000      // N_ENT
#define NR 100        // N_REL2
#define NB 16         // N_BASES
#define D  64         // DIM
#define NE 100000     // N_EDGES

// W[r, k, d] = sum_b att[r, b] * basis[b, k, d]
__global__ __launch_bounds__(256) void compute_w(
    const float* __restrict__ att, const float* __restrict__ basis,
    float* __restrict__ W)
{
    int idx = blockIdx.x * 256 + threadIdx.x;      // over NR*D*D = 409600
    if (idx >= NR * D * D) return;
    int r  = idx / (D * D);
    int kd = idx - r * (D * D);
    float acc = 0.f;
#pragma unroll
    for (int b = 0; b < NB; ++b)
        acc += att[r * NB + b] * basis[b * D * D + kd];
    W[idx] = acc;
}

// x0[n, d] = emb[entity[n], d]
__global__ __launch_bounds__(256) void gather_emb(
    const int* __restrict__ entity, const float* __restrict__ emb,
    float* __restrict__ x0)
{
    int idx = blockIdx.x * 256 + threadIdx.x;      // over NN*D
    if (idx >= NN * D) return;
    int n = idx >> 6;
    int d = idx & 63;
    x0[idx] = emb[entity[n] * D + d];
}

// cnt[dst[e]] += 1 (same for both layers)
__global__ __launch_bounds__(256) void count_edges(
    const int* __restrict__ dst, float* __restrict__ cnt)
{
    int e = blockIdx.x * 256 + threadIdx.x;
    if (e >= NE) return;
    atomicAdd(&cnt[dst[e]], 1.0f);
}

// One wave (64 lanes) per edge: msg = (x[src] @ W[etype]) * norm,
// atomically scattered into s[dst].
// NE = 100000 is divisible by 4 edges/block -> no partial blocks.
__global__ __launch_bounds__(256) void edge_msg(
    const int* __restrict__ src, const int* __restrict__ dst,
    const int* __restrict__ etype, const float* __restrict__ enorm,
    const float* __restrict__ x, const float* __restrict__ W,
    float* __restrict__ s)
{
    int wid  = threadIdx.x >> 6;
    int lane = threadIdx.x & 63;
    int e = blockIdx.x * 4 + wid;

    __shared__ float xs[4][D];
    int sn = src[e];
    xs[wid][lane] = x[sn * D + lane];
    __syncthreads();

    const float* __restrict__ Wr = W + (long)etype[e] * (D * D);
    float acc = 0.f;
#pragma unroll
    for (int k = 0; k < D; ++k)
        acc += xs[wid][k] * Wr[k * D + lane];        // LDS broadcast + coalesced W

    atomicAdd(&s[(long)dst[e] * D + lane], acc * enorm[e]);
}

// out[n] = s[n]/max(cnt[n],1) + x[n] @ root + bias
// Safe for in-place x == out: each wave reads its own row before writing it.
// NN = 50000 divisible by 4 nodes/block -> no partial blocks.
__global__ __launch_bounds__(256) void node_out(
    const float* __restrict__ x, const float* __restrict__ s,
    const float* __restrict__ cnt, const float* __restrict__ root,
    const float* __restrict__ bias, float* __restrict__ out)
{
    int wid  = threadIdx.x >> 6;
    int lane = threadIdx.x & 63;
    int n = blockIdx.x * 4 + wid;

    __shared__ float xs[4][D];
    xs[wid][lane] = x[n * D + lane];
    __syncthreads();

    float acc = 0.f;
#pragma unroll
    for (int k = 0; k < D; ++k)
        acc += xs[wid][k] * root[k * D + lane];

    float c = cnt[n];
    c = c > 1.f ? c : 1.f;
    out[n * D + lane] = s[n * D + lane] / c + acc + bias[lane];
}

extern "C" void kernel_launch(void* const* d_in, const int* in_sizes, int n_in,
                              void* d_out, int out_size, void* d_ws, size_t ws_size,
                              hipStream_t stream) {
    const int*   entity    = (const int*)d_in[0];
    const int*   edge_index= (const int*)d_in[1];    // [2, NE]
    const int*   edge_type = (const int*)d_in[2];
    const float* edge_norm = (const float*)d_in[3];
    const float* emb       = (const float*)d_in[4];
    const float* basis1    = (const float*)d_in[5];
    const float* att1      = (const float*)d_in[6];
    const float* root1     = (const float*)d_in[7];
    const float* bias1     = (const float*)d_in[8];
    const float* basis2    = (const float*)d_in[9];
    const float* att2      = (const float*)d_in[10];
    const float* root2     = (const float*)d_in[11];
    const float* bias2     = (const float*)d_in[12];

    const int* src = edge_index;
    const int* dst = edge_index + NE;

    float* ws  = (float*)d_ws;
    float* x0  = ws;                   // NN*D
    float* s   = x0  + (size_t)NN * D; // NN*D
    float* cnt = s   + (size_t)NN * D; // NN
    float* W   = cnt + NN;             // NR*D*D

    float* out = (float*)d_out;        // serves as x1 and final output

    // zero s + cnt (contiguous)
    hipMemsetAsync(s, 0, ((size_t)NN * D + NN) * sizeof(float), stream);

    gather_emb<<<(NN * D + 255) / 256, 256, 0, stream>>>(entity, emb, x0);
    count_edges<<<(NE + 255) / 256, 256, 0, stream>>>(dst, cnt);

    // ---- layer 1 ----
    compute_w<<<(NR * D * D + 255) / 256, 256, 0, stream>>>(att1, basis1, W);
    edge_msg<<<NE / 4, 256, 0, stream>>>(src, dst, edge_type, edge_norm, x0, W, s);
    node_out<<<NN / 4, 256, 0, stream>>>(x0, s, cnt, root1, bias1, out);

    // ---- layer 2 ----
    hipMemsetAsync(s, 0, (size_t)NN * D * sizeof(float), stream);
    compute_w<<<(NR * D * D + 255) / 256, 256, 0, stream>>>(att2, basis2, W);
    edge_msg<<<NE / 4, 256, 0, stream>>>(src, dst, edge_type, edge_norm, out, W, s);
    node_out<<<NN / 4, 256, 0, stream>>>(out, s, cnt, root2, bias2, out);
}